// Round 10
// baseline (2767.803 us; speedup 1.0000x reference)
//
#include <hip/hip_runtime.h>
#include <math.h>

// ---- problem constants ----
#define NCAM 6
#define CIN  64
#define HF   44
#define WF   80
#define PP   (HF*WF)        // 3520
#define XD   100
#define YD   100
#define ZD   20
#define NVOX (XD*YD*ZD)     // 200000
#define DBN  50
#define VDIM 64
#define FOUT 256
#define EPSF 1e-8f

typedef _Float16 f16x4 __attribute__((ext_vector_type(4)));
typedef _Float16 f16x8 __attribute__((ext_vector_type(8)));
typedef float    f32x4 __attribute__((ext_vector_type(4)));

// ---- workspace layout (bytes). Peak = 160,819,200 B (known-good). ----
// consts:                 [0, 51,200)
// vol    [NVOX][64]:      [51,200, 25,651,200)        alive conv3d -> project
//   wT1 / h overlap vol region after project
// vin    [NVOX][128]:     [25,651,200, 76,851,200)    alive mlp -> conv3d
// wT3    [27][64][128]:   [76,851,200, 77,293,568)
// S      [NVOX][160] f16: [77,294,592, 141,294,592)   alive gather -> mlp
// W2     [128][160] f16:  [141,294,592, 141,335,552)
// featsT [6][3520][64]:   [141,335,552, 144,038,912)  alive tw5 -> gather (dead before proj)
// proj   [21120][3200]:   [25,651,200, 160,819,200)   written after S/W2/featsT dead
#define OFF_KE    0
#define OFF_K3I   96
#define OFF_XI    160
#define OFF_DBIN  260
#define B_VOL     51200UL
#define B_WT1     51200UL
#define B_H       14796800UL
#define B_VIN     25651200UL
#define B_PROJ    25651200UL
#define B_WT2     25651200UL
#define B_WT3     76851200UL
#define B_S       77294592UL
#define B_W2      141294592UL
#define B_FT      141335552UL
#define SK        160                      // padded K for the voxel MLP

__device__ __forceinline__ float eluf(float x) { return x > 0.f ? x : expm1f(x); }

// ego_x axis: ego_x[i] = 1/(a + (99-i)*step)
#define AX_A    (1.0f/51.5f)
#define AX_STEP ((0.5f - 1.0f/51.5f)/99.0f)

__device__ __forceinline__ void inv3x3(const float m[9], float o[9]) {
    float a00 = m[4]*m[8] - m[5]*m[7];
    float a10 = m[5]*m[6] - m[3]*m[8];
    float a20 = m[3]*m[7] - m[4]*m[6];
    float det = m[0]*a00 + m[1]*a10 + m[2]*a20;
    float id = 1.0f/det;
    o[0] = a00*id;
    o[1] = (m[2]*m[7] - m[1]*m[8])*id;
    o[2] = (m[1]*m[5] - m[2]*m[4])*id;
    o[3] = a10*id;
    o[4] = (m[0]*m[8] - m[2]*m[6])*id;
    o[5] = (m[2]*m[3] - m[0]*m[5])*id;
    o[6] = a20*id;
    o[7] = (m[1]*m[6] - m[0]*m[7])*id;
    o[8] = (m[0]*m[4] - m[1]*m[3])*id;
}

__global__ __launch_bounds__(256) void setup_kernel(const float* K, const float* ext,
                                                    float* ws) {
    int t = threadIdx.x;
    if (t < NCAM) {
        const float* E = ext + t*16;
        float R[9] = {E[0],E[1],E[2], E[4],E[5],E[6], E[8],E[9],E[10]};
        float Ri[9];
        inv3x3(R, Ri);
        float tx=E[3], ty=E[7], tz=E[11];
        float bx = -(Ri[0]*tx + Ri[1]*ty + Ri[2]*tz);
        float by = -(Ri[3]*tx + Ri[4]*ty + Ri[5]*tz);
        float bz = -(Ri[6]*tx + Ri[7]*ty + Ri[8]*tz);
        float Ei[16] = {Ri[0],Ri[1],Ri[2],bx, Ri[3],Ri[4],Ri[5],by, Ri[6],Ri[7],Ri[8],bz, 0,0,0,1};
        const float* Km = K + t*16;
        float* KE = ws + OFF_KE + t*16;
        for (int r=0;r<4;r++)
            for (int c=0;c<4;c++) {
                float s=0.f;
                for (int k=0;k<4;k++) s += Km[r*4+k]*Ei[k*4+c];
                KE[r*4+c]=s;
            }
        float Kr[9] = {Km[0],Km[1],Km[2], Km[4],Km[5],Km[6], Km[8],Km[9],Km[10]};
        float Ki[9];
        inv3x3(Kr, Ki);
        float* KI = ws + OFF_K3I + t*9;
        for (int i=0;i<9;i++) KI[i]=Ki[i];
    }
    if (t >= 64 && t < 64+XD) {
        int x = t-64;
        float ex0 = 1.0f/(AX_A + 99.0f*AX_STEP);
        float exN = 1.0f/AX_A;
        float q = 2.0f + (float)x * (49.5f/99.0f);
        float qc = fminf(fmaxf(q, ex0), exN - 1e-6f);
        float f = 99.0f - (1.0f/qc - AX_A)/AX_STEP;
        int k = min(max((int)floorf(f),0),98);
        float exk  = 1.0f/(AX_A + (float)(99-k)*AX_STEP);
        float exk1 = 1.0f/(AX_A + (float)(98-k)*AX_STEP);
        ws[OFF_XI + x] = (float)k + (qc - exk)/(exk1 - exk + 1e-12f);
    }
    if (t >= 192 && t < 192+DBN) {
        int d = t-192;
        float sa = 1.0f/50.0f;
        float ss = (0.5f - sa)/49.0f;
        ws[OFF_DBIN + d] = 1.0f/(sa + (float)(49-d)*ss);
    }
}

// ---- one-shot weight transposes to fp16, [tap][oc][ic] ----
__global__ __launch_bounds__(256) void tw1_kernel(const float* w, _Float16* o) {
    int idx = blockIdx.x*256 + threadIdx.x;   // 9*256*3200
    int cp  = idx % 3200;                     // c' = d*64 + v
    int oc  = (idx/3200) & 255;
    int tap = idx/(3200*256);
    int d = cp >> 6, v = cp & 63;
    o[idx] = (_Float16)w[((size_t)oc*3200 + v*50 + d)*9 + tap];
}
__global__ __launch_bounds__(256) void tw2_kernel(const float* w, _Float16* o) {
    int idx = blockIdx.x*256 + threadIdx.x;   // 9*256*256
    int ic  = idx & 255;
    int oc  = (idx >> 8) & 255;
    int tap = idx >> 16;
    o[idx] = (_Float16)w[((size_t)oc*256 + ic)*9 + tap];
}
__global__ __launch_bounds__(256) void tw3_kernel(const float* w, _Float16* o) {
    int idx = blockIdx.x*256 + threadIdx.x;   // 27*64*128
    int ci  = idx & 127;
    int oc  = (idx >> 7) & 63;
    int tap = idx >> 13;
    o[idx] = (_Float16)w[((size_t)oc*128 + ci)*27 + tap];
}
// W2[128][160]: rows 0-63 = w_ov remapped, rows 64-127 = w_no duplicated; zeros elsewhere
__global__ __launch_bounds__(256) void tw4_kernel(const float* w_ov, const float* w_no,
                                                  _Float16* o) {
    int idx = blockIdx.x*256 + threadIdx.x;   // 128*160 = 20480
    int k = idx % SK;
    int r = idx / SK;
    float v = 0.f;
    if (r < 64) {
        if (k < 64)                 v = w_ov[r*130 + k];
        else if (k == 64)           v = w_ov[r*130 + 64];
        else if (k >= 66 && k < 130) v = w_ov[r*130 + 65 + (k-66)];
        else if (k == 130)          v = w_ov[r*130 + 129];
    } else {
        int rr = r - 64;
        if (k < 64)                 v = w_no[rr*65 + k];
        else if (k == 64)           v = w_no[rr*65 + 64];
        else if (k >= 66 && k < 130) v = w_no[rr*65 + (k-66)];
        else if (k == 130)          v = w_no[rr*65 + 64];
    }
    o[idx] = (_Float16)v;
}
// feats transpose: [cam][ch][pix] f32 -> [cam][pix][ch] f16 (coalesced gather reads)
__global__ __launch_bounds__(256) void tw5_kernel(const float* feats, _Float16* o) {
    int idx = blockIdx.x*256 + threadIdx.x;   // 6*3520*64 = 1,351,680
    int ch = idx & 63;
    int p  = (idx >> 6) % PP;
    int cam = idx / (64*PP);
    o[idx] = (_Float16)feats[((size_t)(cam*64 + ch))*PP + p];
}

// gather-only backprojection: one wave per voxel, lane = channel; coalesced featsT reads
__global__ __launch_bounds__(256) void gather_kernel(const _Float16* featsT, const float* masks,
                                                     const float* ws, _Float16* S) {
    int wave = threadIdx.x >> 6;
    int lane = threadIdx.x & 63;
    int n = blockIdx.x*4 + wave;
    int x = n % XD;
    int y = (n / XD) % YD;
    int z = n / (XD*YD);
    float gx = 1.0f/(AX_A + (float)(99-x)*AX_STEP);
    float gy = -25.0f + (float)y * (49.5f/99.0f);
    float gz = -3.0f  + (float)z * (5.7f/19.0f);

    float sA = 0.f, sB = 0.f, sA64 = 0.f, sB64 = 0.f;
    int cnt = 0;
    for (int cam = 0; cam < NCAM; ++cam) {
        const float* KE = ws + OFF_KE + cam*16;
        float px = KE[0]*gx + KE[1]*gy + KE[2]*gz + KE[3];
        float py = KE[4]*gx + KE[5]*gy + KE[6]*gz + KE[7];
        float pz = KE[8]*gx + KE[9]*gy + KE[10]*gz + KE[11];
        float inv = 1.0f/(pz + EPSF);
        float u = px*inv, v = py*inv;
        bool valid = (pz > EPSF) && (u >= 0.f) && (u <= 79.f) && (v >= 0.f) && (v <= 43.f);
        if (valid) {   // wave-uniform
            cnt++;
            float u0 = floorf(u), v0 = floorf(v);
            float du = u-u0, dv = v-v0;
            int u0i = min(max((int)u0,0),WF-1), u1i = min(u0i+1,WF-1);
            int v0i = min(max((int)v0,0),HF-1), v1i = min(v0i+1,HF-1);
            float w00=(1.f-du)*(1.f-dv), w01=du*(1.f-dv), w10=(1.f-du)*dv, w11=du*dv;
            int i00=v0i*WF+u0i, i01=v0i*WF+u1i, i10=v1i*WF+u0i, i11=v1i*WF+u1i;
            const _Float16* img = featsT + (size_t)cam*PP*64;
            float val = w00*(float)img[(size_t)i00*64 + lane]
                      + w01*(float)img[(size_t)i01*64 + lane]
                      + w10*(float)img[(size_t)i10*64 + lane]
                      + w11*(float)img[(size_t)i11*64 + lane];
            const float* mg = masks + cam*PP;
            float mv = w00*mg[i00] + w01*mg[i01] + w10*mg[i10] + w11*mg[i11];
            if (cam < 3) { sA += val; sA64 += mv; }
            else         { sB += val; sB64 += mv; }
        }
    }
    _Float16* Sp = S + (size_t)n*SK;
    Sp[lane]      = (_Float16)sA;     // k = 0..63
    Sp[66 + lane] = (_Float16)sB;     // k = 66..129
    if (lane == 0) { Sp[64] = (_Float16)sA64; Sp[130] = (_Float16)sB64; }
    if (lane == 1) Sp[65] = (_Float16)0.f;
    if (lane >= 3 && lane <= 30) Sp[131 + (lane-3)] = (_Float16)0.f;   // 131..158
    if (lane == 31) Sp[159] = (_Float16)(float)cnt;                    // cnt channel
}

// voxel MLP as MFMA GEMM: out[128, N] = W2[128,160] @ S[160, N]; cnt-select epilogue.
__global__ __launch_bounds__(256,2) void mlp_kernel(const _Float16* __restrict__ S,
                                                    const _Float16* __restrict__ W2,
                                                    const float* __restrict__ b_ov,
                                                    const float* __restrict__ b_no,
                                                    _Float16* __restrict__ vin) {
    constexpr int WPAD = 168;                       // padded LDS row (2-way banks)
    __shared__ __align__(16) _Float16 Wl[128*WPAD]; // 43 KB
    int tid = threadIdx.x, lane = tid & 63, wave = tid >> 6;
    int ln = lane & 15, kq = lane >> 4;
    for (int i = tid; i < 128*20; i += 256) {       // 20 granules of 8 per row
        int r = i / 20, g8 = i % 20;
        *(f16x8*)(&Wl[r*WPAD + g8*8]) = *(const f16x8*)(W2 + r*SK + g8*8);
    }
    __syncthreads();

    int nbase = blockIdx.x*128 + wave*32;           // this wave's 32 voxels
    f32x4 zero4 = {0.f,0.f,0.f,0.f};
    f32x4 acc[8][2];
    for (int m=0;m<8;m++) for (int t=0;t<2;t++) acc[m][t] = zero4;

    for (int ks = 0; ks < 5; ++ks) {
        int k0 = ks*32 + kq*8;
        f16x8 b0, b1;
        {
            int c0 = min(nbase + ln,      NVOX-1);
            int c1 = min(nbase + 16 + ln, NVOX-1);
            b0 = *(const f16x8*)(S + (size_t)c0*SK + k0);
            b1 = *(const f16x8*)(S + (size_t)c1*SK + k0);
        }
        #pragma unroll
        for (int m = 0; m < 8; ++m) {
            f16x8 a = *(const f16x8*)(&Wl[(m*16 + ln)*WPAD + k0]);
            acc[m][0] = __builtin_amdgcn_mfma_f32_16x16x32_f16(a, b0, acc[m][0], 0,0,0);
            acc[m][1] = __builtin_amdgcn_mfma_f32_16x16x32_f16(a, b1, acc[m][1], 0,0,0);
        }
    }
    #pragma unroll
    for (int t = 0; t < 2; ++t) {
        int col = nbase + t*16 + ln;
        if (col >= NVOX) continue;
        float cnt = (float)S[(size_t)col*SK + 159];
        #pragma unroll
        for (int m = 0; m < 4; ++m) {
            int oc0 = m*16 + kq*4;
            f32x4 bov = *(const f32x4*)(b_ov + oc0);
            f32x4 bno = *(const f32x4*)(b_no + oc0);
            f16x4 s;
            #pragma unroll
            for (int r = 0; r < 4; ++r) {
                float v = 0.f;
                if (cnt == 2.f)      v = eluf(acc[m][t][r]   + bov[r]);
                else if (cnt == 1.f) v = eluf(acc[m+4][t][r] + bno[r]);
                s[r] = (_Float16)v;
            }
            *(f16x4*)(vin + (size_t)col*128 + oc0) = s;
        }
    }
}

// vf_remap: x-lerp onto uniform grid; wave per voxel, lane = channel; writes ch [64,128)
__global__ __launch_bounds__(256) void remap_kernel(const float* ws, _Float16* vin) {
    int wave = threadIdx.x >> 6, lane = threadIdx.x & 63;
    int n = blockIdx.x*4 + wave;
    int x = n % XD;
    float xi = ws[OFF_XI + x];
    float fx = floorf(xi);
    float t = xi - fx;
    int x0 = min(max((int)fx,0),XD-1);
    int x1 = min(x0+1, XD-1);
    size_t rowb = (size_t)(n - x)*128;
    float r = (float)vin[rowb + (size_t)x0*128 + lane]*(1.f-t)
            + (float)vin[rowb + (size_t)x1*128 + lane]*t;
    vin[(size_t)n*128 + 64 + lane] = (_Float16)r;
}

// ---- conv3d as implicit GEMM: M=64 oc, K=128ci x 27 taps, N = one x-row ----
__global__ __launch_bounds__(256,2) void conv3d_mfma_kernel(const _Float16* __restrict__ vin,
                                                            const _Float16* __restrict__ wT,
                                                            const float* __restrict__ bias,
                                                            _Float16* __restrict__ vol) {
    __shared__ __align__(16) _Float16 Bs[9*104*36];   // [zy-row][x_ext][ic32 pad36]
    int tid = threadIdx.x, lane = tid & 63, wave = tid >> 6;
    int ln = lane & 15, kq = lane >> 4;
    int y = blockIdx.x % 100, z = blockIdx.x / 100;
    int nt0 = wave*2;
    int ntn = (wave == 3) ? 1 : 2;
    f32x4 zero4 = {0.f,0.f,0.f,0.f};
    f32x4 acc[4][2];
    for (int i=0;i<4;i++) for (int t=0;t<2;t++) acc[i][t] = zero4;

    for (int c0 = 0; c0 < 128; c0 += 32) {
        __syncthreads();
        for (int g = tid; g < 9*104*4; g += 256) {
            int ic8 = g & 3;
            int xe  = (g >> 2) % 104;
            int rid = g / (104*4);
            int xx = xe - 1, yy = y + rid%3 - 1, zz = z + rid/3 - 1;
            f16x8 val = {0,0,0,0,0,0,0,0};
            if (xx >= 0 && xx < 100 && yy >= 0 && yy < 100 && zz >= 0 && zz < 20)
                val = *(const f16x8*)(vin + (size_t)((zz*100 + yy)*100 + xx)*128 + c0 + ic8*8);
            *(f16x8*)(&Bs[(rid*104 + xe)*36 + ic8*8]) = val;
        }
        __syncthreads();
        const _Float16* wp0 = wT + c0 + kq*8;
        f16x8 a0n = *(const f16x8*)(wp0 + (ln+ 0)*128);
        f16x8 a1n = *(const f16x8*)(wp0 + (ln+16)*128);
        f16x8 a2n = *(const f16x8*)(wp0 + (ln+32)*128);
        f16x8 a3n = *(const f16x8*)(wp0 + (ln+48)*128);
        for (int tap = 0; tap < 27; ++tap) {
            f16x8 a0 = a0n, a1 = a1n, a2 = a2n, a3 = a3n;
            if (tap < 26) {
                const _Float16* wp = wT + (size_t)(tap+1)*64*128 + c0 + kq*8;
                a0n = *(const f16x8*)(wp + (ln+ 0)*128);
                a1n = *(const f16x8*)(wp + (ln+16)*128);
                a2n = *(const f16x8*)(wp + (ln+32)*128);
                a3n = *(const f16x8*)(wp + (ln+48)*128);
            }
            int dx = tap % 3, rid = tap / 3;      // rid = dz*3+dy
            for (int t = 0; t < ntn; ++t) {
                int xe = min(16*(nt0+t) + ln + dx, 103);
                f16x8 b = *(const f16x8*)(&Bs[(rid*104 + xe)*36 + kq*8]);
                acc[0][t] = __builtin_amdgcn_mfma_f32_16x16x32_f16(a0, b, acc[0][t], 0,0,0);
                acc[1][t] = __builtin_amdgcn_mfma_f32_16x16x32_f16(a1, b, acc[1][t], 0,0,0);
                acc[2][t] = __builtin_amdgcn_mfma_f32_16x16x32_f16(a2, b, acc[2][t], 0,0,0);
                acc[3][t] = __builtin_amdgcn_mfma_f32_16x16x32_f16(a3, b, acc[3][t], 0,0,0);
            }
        }
    }
    for (int i = 0; i < 4; ++i) {
        int oc0 = i*16 + kq*4;
        f32x4 bv = *(const f32x4*)(bias + oc0);
        for (int t = 0; t < ntn; ++t) {
            int x = 16*(nt0+t) + ln;
            if (x < 100) {
                size_t n = (size_t)(z*100 + y)*100 + x;
                f16x4 s;
                s[0] = (_Float16)eluf(acc[i][t][0] + bv[0]);
                s[1] = (_Float16)eluf(acc[i][t][1] + bv[1]);
                s[2] = (_Float16)eluf(acc[i][t][2] + bv[2]);
                s[3] = (_Float16)eluf(acc[i][t][3] + bv[3]);
                *(f16x4*)(vol + n*64 + oc0) = s;
            }
        }
    }
}

// ---- project: two-phase (unchanged) ----
__global__ __launch_bounds__(256) void project_kernel(const float* ws, const float* ext,
                                                      const _Float16* vol, _Float16* proj) {
    __shared__ unsigned s_off[256][8];
    __shared__ float    s_w[256][8];
    int tid = threadIdx.x;
    int item = blockIdx.x*256 + tid;       // item = (cam*3520 + p)*50 + d
    int d = item % 50;
    int p = (item/50) % 3520;
    int cam = item / (50*3520);
    {
        float uu = (float)(p % WF), vv = (float)(p / WF);
        const float* KI = ws + OFF_K3I + cam*9;
        float dxr = KI[0]*uu + KI[1]*vv + KI[2];
        float dyr = KI[3]*uu + KI[4]*vv + KI[5];
        float dzr = KI[6]*uu + KI[7]*vv + KI[8];
        float dep = ws[OFF_DBIN + d];
        float cx = dxr*dep, cy = dyr*dep, cz = dzr*dep;
        const float* E = ext + cam*16;
        float wx = E[0]*cx + E[1]*cy + E[2]*cz  + E[3];
        float wy = E[4]*cx + E[5]*cy + E[6]*cz  + E[7];
        float wz = E[8]*cx + E[9]*cy + E[10]*cz + E[11];
        float ex0 = 1.0f/(AX_A + 99.0f*AX_STEP);
        float exN = 1.0f/AX_A;
        float qc = fminf(fmaxf(wx, ex0), exN - 1e-6f);
        float f = 99.0f - (1.0f/qc - AX_A)/AX_STEP;
        int k = min(max((int)floorf(f),0),98);
        float exk  = 1.0f/(AX_A + (float)(99-k)*AX_STEP);
        float exk1 = 1.0f/(AX_A + (float)(98-k)*AX_STEP);
        float xi = (float)k + (qc - exk)/(exk1 - exk + 1e-12f);
        float yi = (wy + 25.0f) * (99.0f/49.5f);
        float zi = (wz + 3.0f)  * (19.0f/5.7f);
        float scale = ((wx >= 2.0f) && (wx <= 51.5f) && (yi >= 0.f) && (yi <= 99.f)
                       && (zi >= 0.f) && (zi <= 19.f)) ? 1.f : 0.f;
        float fx = floorf(xi), fy = floorf(yi), fz = floorf(zi);
        float tx = xi-fx, ty = yi-fy, tz = zi-fz;
        int x0 = min(max((int)fx,0),XD-1), x1 = min(x0+1,XD-1);
        int y0 = min(max((int)fy,0),YD-1), y1 = min(y0+1,YD-1);
        int z0 = min(max((int)fz,0),ZD-1), z1 = min(z0+1,ZD-1);
        s_off[tid][0] = (unsigned)(((z0*YD+y0)*XD+x0)*64); s_w[tid][0] = (1.f-tx)*(1.f-ty)*(1.f-tz)*scale;
        s_off[tid][1] = (unsigned)(((z0*YD+y0)*XD+x1)*64); s_w[tid][1] = tx*(1.f-ty)*(1.f-tz)*scale;
        s_off[tid][2] = (unsigned)(((z0*YD+y1)*XD+x0)*64); s_w[tid][2] = (1.f-tx)*ty*(1.f-tz)*scale;
        s_off[tid][3] = (unsigned)(((z0*YD+y1)*XD+x1)*64); s_w[tid][3] = tx*ty*(1.f-tz)*scale;
        s_off[tid][4] = (unsigned)(((z1*YD+y0)*XD+x0)*64); s_w[tid][4] = (1.f-tx)*(1.f-ty)*tz*scale;
        s_off[tid][5] = (unsigned)(((z1*YD+y0)*XD+x1)*64); s_w[tid][5] = tx*(1.f-ty)*tz*scale;
        s_off[tid][6] = (unsigned)(((z1*YD+y1)*XD+x0)*64); s_w[tid][6] = (1.f-tx)*ty*tz*scale;
        s_off[tid][7] = (unsigned)(((z1*YD+y1)*XD+x1)*64); s_w[tid][7] = tx*ty*tz*scale;
    }
    __syncthreads();
    int wave = tid >> 6, lane = tid & 63;
    size_t outbase = (size_t)blockIdx.x*256 + wave*64;
    for (int j = 0; j < 64; ++j) {
        int it = wave*64 + j;
        float a = 0.f;
        #pragma unroll
        for (int c = 0; c < 8; ++c)
            a += s_w[it][c] * (float)vol[s_off[it][c] + lane];
        proj[(outbase + j)*64 + lane] = (_Float16)a;
    }
}

// ---- conv2d implicit GEMM: R5 config + A double-buffer across chunks.
//      Per chunk both A(18 frags) and B(6 slots) for chunk c+1 are issued while chunk c's
//      MFMAs run on registers — the only waits left are one vmcnt rendezvous per chunk.
template<int ICN, bool OUT16>
__global__ __launch_bounds__(256,2) void conv2d_mfma_kernel(const _Float16* __restrict__ in,
                                                            const _Float16* __restrict__ wT,
                                                            const float* __restrict__ bias,
                                                            void* __restrict__ outp) {
    constexpr int NCH = ICN/32;
    constexpr int NSLOT = 6;                          // ceil(4*82*4 / 256)
    __shared__ __align__(16) _Float16 Bs[2][4*82*36]; // 2 x 23.6 KB
    int tid = threadIdx.x, lane = tid & 63, wave = tid >> 6;
    int wm = wave >> 1, wn = wave & 1;
    int ln = lane & 15, kq = lane >> 4;
    int bid = blockIdx.x;
    int ocq = bid & 3;
    int rest = bid >> 2;
    int cam = rest % 6;
    int h0 = (rest / 6)*2;
    int ocb = ocq*64 + wm*32;
    size_t campix0 = (size_t)cam*3520;
    f32x4 zero4 = {0.f,0.f,0.f,0.f};
    f32x4 acc[2][5];
    for (int i=0;i<2;i++) for (int t=0;t<5;t++) acc[i][t] = zero4;

    // staging slot descriptors
    size_t soff[NSLOT];
    int    slds[NSLOT];
    bool   sok[NSLOT];
    #pragma unroll
    for (int i = 0; i < NSLOT; ++i) {
        int g = tid + i*256;
        if (g < 4*82*4) {
            int ic8 = g & 3;
            int we  = (g >> 2) % 82;
            int re  = g / (82*4);
            int h = h0 - 1 + re;
            int w = we - 1;
            sok[i]  = (h >= 0 && h < HF && w >= 0 && w < WF);
            soff[i] = (campix0 + h*80 + w)*(size_t)ICN + ic8*8;
            slds[i] = (re*82 + we)*36 + ic8*8;
        } else { sok[i] = false; soff[i] = 0; slds[i] = -1; }
    }

    // prefetch chunk 0: B into sreg, A into Abuf[0]
    f16x8 sreg[NSLOT];
    #pragma unroll
    for (int i = 0; i < NSLOT; ++i) {
        f16x8 v = {0,0,0,0,0,0,0,0};
        if (sok[i]) v = *(const f16x8*)(in + soff[i]);
        sreg[i] = v;
    }
    const _Float16* wbase0 = wT + (size_t)ocb*ICN + kq*8;
    f16x8 A0[2][9], A1[2][9];
    #pragma unroll
    for (int tap = 0; tap < 9; ++tap) {
        const _Float16* wp = wbase0 + (size_t)tap*256*ICN;
        A0[0][tap] = *(const f16x8*)(wp + (size_t)(ln+ 0)*ICN);
        A1[0][tap] = *(const f16x8*)(wp + (size_t)(ln+16)*ICN);
    }

    for (int c = 0; c < NCH; ++c) {
        int buf = c & 1, nxt = buf ^ 1;
        #pragma unroll
        for (int i = 0; i < NSLOT; ++i)
            if (slds[i] >= 0) *(f16x8*)(&Bs[buf][slds[i]]) = sreg[i];
        __syncthreads();
        // prefetch chunk c+1: B then A — consumed only at next iteration
        if (c + 1 < NCH) {
            int c1 = (c+1)*32;
            #pragma unroll
            for (int i = 0; i < NSLOT; ++i) {
                f16x8 v = {0,0,0,0,0,0,0,0};
                if (sok[i]) v = *(const f16x8*)(in + soff[i] + c1);
                sreg[i] = v;
            }
            const _Float16* wb = wbase0 + c1;
            #pragma unroll
            for (int tap = 0; tap < 9; ++tap) {
                const _Float16* wp = wb + (size_t)tap*256*ICN;
                A0[nxt][tap] = *(const f16x8*)(wp + (size_t)(ln+ 0)*ICN);
                A1[nxt][tap] = *(const f16x8*)(wp + (size_t)(ln+16)*ICN);
            }
        }
        #pragma unroll
        for (int tap = 0; tap < 9; ++tap) {
            int ky = tap/3, kx = tap%3;
            int rbase = (wn + ky)*82 + ln + kx;
            #pragma unroll
            for (int t = 0; t < 5; ++t) {
                f16x8 b = *(const f16x8*)(&Bs[buf][(rbase + 16*t)*36 + kq*8]);
                acc[0][t] = __builtin_amdgcn_mfma_f32_16x16x32_f16(A0[buf][tap], b, acc[0][t], 0,0,0);
                acc[1][t] = __builtin_amdgcn_mfma_f32_16x16x32_f16(A1[buf][tap], b, acc[1][t], 0,0,0);
            }
        }
    }
    int pixrow = h0 + wn;
    for (int i = 0; i < 2; ++i) {
        int oc0 = ocb + i*16 + kq*4;
        f32x4 bv = *(const f32x4*)(bias + oc0);
        for (int t = 0; t < 5; ++t) {
            int pix = pixrow*80 + 16*t + ln;
            float v0 = eluf(acc[i][t][0] + bv[0]);
            float v1 = eluf(acc[i][t][1] + bv[1]);
            float v2 = eluf(acc[i][t][2] + bv[2]);
            float v3 = eluf(acc[i][t][3] + bv[3]);
            if (OUT16) {
                f16x4 s; s[0]=(_Float16)v0; s[1]=(_Float16)v1; s[2]=(_Float16)v2; s[3]=(_Float16)v3;
                *(f16x4*)((_Float16*)outp + (campix0 + pix)*256 + oc0) = s;
            } else {
                float* op = (float*)outp + ((size_t)(cam*256 + oc0))*PP + pix;
                op[0] = v0; op[PP] = v1; op[2*PP] = v2; op[3*PP] = v3;
            }
        }
    }
}

extern "C" void kernel_launch(void* const* d_in, const int* in_sizes, int n_in,
                              void* d_out, int out_size, void* d_ws, size_t ws_size,
                              hipStream_t stream) {
    const float* feats = (const float*)d_in[0];
    const float* masks = (const float*)d_in[1];
    const float* K     = (const float*)d_in[2];
    const float* ext   = (const float*)d_in[3];
    const float* w_ov  = (const float*)d_in[4];
    const float* b_ov  = (const float*)d_in[5];
    const float* w_no  = (const float*)d_in[6];
    const float* b_no  = (const float*)d_in[7];
    const float* w_fu  = (const float*)d_in[8];
    const float* b_fu  = (const float*)d_in[9];
    const float* w_r1  = (const float*)d_in[10];
    const float* b_r1  = (const float*)d_in[11];
    const float* w_r2  = (const float*)d_in[12];
    const float* b_r2  = (const float*)d_in[13];
    char* base = (char*)d_ws;
    float*    wsf  = (float*)base;
    _Float16* vol  = (_Float16*)(base + B_VOL);
    _Float16* wT1  = (_Float16*)(base + B_WT1);
    _Float16* h    = (_Float16*)(base + B_H);
    _Float16* vin  = (_Float16*)(base + B_VIN);
    _Float16* proj = (_Float16*)(base + B_PROJ);
    _Float16* wT2  = (_Float16*)(base + B_WT2);
    _Float16* wT3  = (_Float16*)(base + B_WT3);
    _Float16* Sbuf = (_Float16*)(base + B_S);
    _Float16* W2   = (_Float16*)(base + B_W2);
    _Float16* fT   = (_Float16*)(base + B_FT);
    float* out = (float*)d_out;

    setup_kernel<<<1, 256, 0, stream>>>(K, ext, wsf);
    tw3_kernel<<<(27*64*128)/256, 256, 0, stream>>>(w_fu, wT3);
    tw4_kernel<<<(128*SK)/256, 256, 0, stream>>>(w_ov, w_no, W2);
    tw5_kernel<<<(NCAM*PP*64)/256, 256, 0, stream>>>(feats, fT);
    gather_kernel<<<NVOX/4, 256, 0, stream>>>(fT, masks, wsf, Sbuf);
    mlp_kernel<<<(NVOX + 127)/128, 256, 0, stream>>>(Sbuf, W2, b_ov, b_no, vin);
    remap_kernel<<<NVOX/4, 256, 0, stream>>>(wsf, vin);
    conv3d_mfma_kernel<<<ZD*YD, 256, 0, stream>>>(vin, wT3, b_fu, vol);
    project_kernel<<<(NCAM*PP*DBN)/256, 256, 0, stream>>>(wsf, ext, vol, proj);
    tw1_kernel<<<(9*256*3200)/256, 256, 0, stream>>>(w_r1, wT1);
    conv2d_mfma_kernel<3200, true><<<4*NCAM*22, 256, 0, stream>>>(proj, wT1, b_r1, h);
    tw2_kernel<<<(9*256*256)/256, 256, 0, stream>>>(w_r2, wT2);
    conv2d_mfma_kernel<256, false><<<4*NCAM*22, 256, 0, stream>>>(h, wT2, b_r2, out);
}

// Round 11
// 1637.513 us; speedup vs baseline: 1.6902x; 1.6902x over previous
//
#include <hip/hip_runtime.h>
#include <math.h>

// ---- problem constants ----
#define NCAM 6
#define CIN  64
#define HF   44
#define WF   80
#define PP   (HF*WF)        // 3520
#define XD   100
#define YD   100
#define ZD   20
#define NVOX (XD*YD*ZD)     // 200000
#define DBN  50
#define VDIM 64
#define FOUT 256
#define EPSF 1e-8f

typedef _Float16 f16x4 __attribute__((ext_vector_type(4)));
typedef _Float16 f16x8 __attribute__((ext_vector_type(8)));
typedef float    f32x4 __attribute__((ext_vector_type(4)));

// ---- workspace layout (bytes). Peak = 160,819,200 B (known-good). ----
// consts:                 [0, 51,200)
// vol    [NVOX][64]:      [51,200, 25,651,200)        alive conv3d -> project
//   wT1 / h overlap vol region after project
// vin    [NVOX][128]:     [25,651,200, 76,851,200)    alive mlp -> conv3d
// wT3    [27][64][128]:   [76,851,200, 77,293,568)
// S      [NVOX][160] f16: [77,294,592, 141,294,592)   alive gather -> mlp
// W2     [128][160] f16:  [141,294,592, 141,335,552)
// featsT [6][3520][64]:   [141,335,552, 144,038,912)  alive tw5 -> gather (dead before proj)
// proj   [21120][3200]:   [25,651,200, 160,819,200)   written after S/W2/featsT dead
#define OFF_KE    0
#define OFF_K3I   96
#define OFF_XI    160
#define OFF_DBIN  260
#define B_VOL     51200UL
#define B_WT1     51200UL
#define B_H       14796800UL
#define B_VIN     25651200UL
#define B_PROJ    25651200UL
#define B_WT2     25651200UL
#define B_WT3     76851200UL
#define B_S       77294592UL
#define B_W2      141294592UL
#define B_FT      141335552UL
#define SK        160                      // padded K for the voxel MLP

__device__ __forceinline__ float eluf(float x) { return x > 0.f ? x : expm1f(x); }

// ego_x axis: ego_x[i] = 1/(a + (99-i)*step)
#define AX_A    (1.0f/51.5f)
#define AX_STEP ((0.5f - 1.0f/51.5f)/99.0f)

__device__ __forceinline__ void inv3x3(const float m[9], float o[9]) {
    float a00 = m[4]*m[8] - m[5]*m[7];
    float a10 = m[5]*m[6] - m[3]*m[8];
    float a20 = m[3]*m[7] - m[4]*m[6];
    float det = m[0]*a00 + m[1]*a10 + m[2]*a20;
    float id = 1.0f/det;
    o[0] = a00*id;
    o[1] = (m[2]*m[7] - m[1]*m[8])*id;
    o[2] = (m[1]*m[5] - m[2]*m[4])*id;
    o[3] = a10*id;
    o[4] = (m[0]*m[8] - m[2]*m[6])*id;
    o[5] = (m[2]*m[3] - m[0]*m[5])*id;
    o[6] = a20*id;
    o[7] = (m[1]*m[6] - m[0]*m[7])*id;
    o[8] = (m[0]*m[4] - m[1]*m[3])*id;
}

__global__ __launch_bounds__(256) void setup_kernel(const float* K, const float* ext,
                                                    float* ws) {
    int t = threadIdx.x;
    if (t < NCAM) {
        const float* E = ext + t*16;
        float R[9] = {E[0],E[1],E[2], E[4],E[5],E[6], E[8],E[9],E[10]};
        float Ri[9];
        inv3x3(R, Ri);
        float tx=E[3], ty=E[7], tz=E[11];
        float bx = -(Ri[0]*tx + Ri[1]*ty + Ri[2]*tz);
        float by = -(Ri[3]*tx + Ri[4]*ty + Ri[5]*tz);
        float bz = -(Ri[6]*tx + Ri[7]*ty + Ri[8]*tz);
        float Ei[16] = {Ri[0],Ri[1],Ri[2],bx, Ri[3],Ri[4],Ri[5],by, Ri[6],Ri[7],Ri[8],bz, 0,0,0,1};
        const float* Km = K + t*16;
        float* KE = ws + OFF_KE + t*16;
        for (int r=0;r<4;r++)
            for (int c=0;c<4;c++) {
                float s=0.f;
                for (int k=0;k<4;k++) s += Km[r*4+k]*Ei[k*4+c];
                KE[r*4+c]=s;
            }
        float Kr[9] = {Km[0],Km[1],Km[2], Km[4],Km[5],Km[6], Km[8],Km[9],Km[10]};
        float Ki[9];
        inv3x3(Kr, Ki);
        float* KI = ws + OFF_K3I + t*9;
        for (int i=0;i<9;i++) KI[i]=Ki[i];
    }
    if (t >= 64 && t < 64+XD) {
        int x = t-64;
        float ex0 = 1.0f/(AX_A + 99.0f*AX_STEP);
        float exN = 1.0f/AX_A;
        float q = 2.0f + (float)x * (49.5f/99.0f);
        float qc = fminf(fmaxf(q, ex0), exN - 1e-6f);
        float f = 99.0f - (1.0f/qc - AX_A)/AX_STEP;
        int k = min(max((int)floorf(f),0),98);
        float exk  = 1.0f/(AX_A + (float)(99-k)*AX_STEP);
        float exk1 = 1.0f/(AX_A + (float)(98-k)*AX_STEP);
        ws[OFF_XI + x] = (float)k + (qc - exk)/(exk1 - exk + 1e-12f);
    }
    if (t >= 192 && t < 192+DBN) {
        int d = t-192;
        float sa = 1.0f/50.0f;
        float ss = (0.5f - sa)/49.0f;
        ws[OFF_DBIN + d] = 1.0f/(sa + (float)(49-d)*ss);
    }
}

// ---- one-shot weight transposes to fp16, [tap][oc][ic] ----
__global__ __launch_bounds__(256) void tw1_kernel(const float* w, _Float16* o) {
    int idx = blockIdx.x*256 + threadIdx.x;   // 9*256*3200
    int cp  = idx % 3200;                     // c' = d*64 + v
    int oc  = (idx/3200) & 255;
    int tap = idx/(3200*256);
    int d = cp >> 6, v = cp & 63;
    o[idx] = (_Float16)w[((size_t)oc*3200 + v*50 + d)*9 + tap];
}
__global__ __launch_bounds__(256) void tw2_kernel(const float* w, _Float16* o) {
    int idx = blockIdx.x*256 + threadIdx.x;   // 9*256*256
    int ic  = idx & 255;
    int oc  = (idx >> 8) & 255;
    int tap = idx >> 16;
    o[idx] = (_Float16)w[((size_t)oc*256 + ic)*9 + tap];
}
__global__ __launch_bounds__(256) void tw3_kernel(const float* w, _Float16* o) {
    int idx = blockIdx.x*256 + threadIdx.x;   // 27*64*128
    int ci  = idx & 127;
    int oc  = (idx >> 7) & 63;
    int tap = idx >> 13;
    o[idx] = (_Float16)w[((size_t)oc*128 + ci)*27 + tap];
}
// W2[128][160]: rows 0-63 = w_ov remapped, rows 64-127 = w_no duplicated; zeros elsewhere
__global__ __launch_bounds__(256) void tw4_kernel(const float* w_ov, const float* w_no,
                                                  _Float16* o) {
    int idx = blockIdx.x*256 + threadIdx.x;   // 128*160 = 20480
    int k = idx % SK;
    int r = idx / SK;
    float v = 0.f;
    if (r < 64) {
        if (k < 64)                 v = w_ov[r*130 + k];
        else if (k == 64)           v = w_ov[r*130 + 64];
        else if (k >= 66 && k < 130) v = w_ov[r*130 + 65 + (k-66)];
        else if (k == 130)          v = w_ov[r*130 + 129];
    } else {
        int rr = r - 64;
        if (k < 64)                 v = w_no[rr*65 + k];
        else if (k == 64)           v = w_no[rr*65 + 64];
        else if (k >= 66 && k < 130) v = w_no[rr*65 + (k-66)];
        else if (k == 130)          v = w_no[rr*65 + 64];
    }
    o[idx] = (_Float16)v;
}
// feats transpose: [cam][ch][pix] f32 -> [cam][pix][ch] f16 (coalesced gather reads)
__global__ __launch_bounds__(256) void tw5_kernel(const float* feats, _Float16* o) {
    int idx = blockIdx.x*256 + threadIdx.x;   // 6*3520*64 = 1,351,680
    int ch = idx & 63;
    int p  = (idx >> 6) % PP;
    int cam = idx / (64*PP);
    o[idx] = (_Float16)feats[((size_t)(cam*64 + ch))*PP + p];
}

// gather-only backprojection: one wave per voxel, lane = channel; coalesced featsT reads
__global__ __launch_bounds__(256) void gather_kernel(const _Float16* featsT, const float* masks,
                                                     const float* ws, _Float16* S) {
    int wave = threadIdx.x >> 6;
    int lane = threadIdx.x & 63;
    int n = blockIdx.x*4 + wave;
    int x = n % XD;
    int y = (n / XD) % YD;
    int z = n / (XD*YD);
    float gx = 1.0f/(AX_A + (float)(99-x)*AX_STEP);
    float gy = -25.0f + (float)y * (49.5f/99.0f);
    float gz = -3.0f  + (float)z * (5.7f/19.0f);

    float sA = 0.f, sB = 0.f, sA64 = 0.f, sB64 = 0.f;
    int cnt = 0;
    for (int cam = 0; cam < NCAM; ++cam) {
        const float* KE = ws + OFF_KE + cam*16;
        float px = KE[0]*gx + KE[1]*gy + KE[2]*gz + KE[3];
        float py = KE[4]*gx + KE[5]*gy + KE[6]*gz + KE[7];
        float pz = KE[8]*gx + KE[9]*gy + KE[10]*gz + KE[11];
        float inv = 1.0f/(pz + EPSF);
        float u = px*inv, v = py*inv;
        bool valid = (pz > EPSF) && (u >= 0.f) && (u <= 79.f) && (v >= 0.f) && (v <= 43.f);
        if (valid) {   // wave-uniform
            cnt++;
            float u0 = floorf(u), v0 = floorf(v);
            float du = u-u0, dv = v-v0;
            int u0i = min(max((int)u0,0),WF-1), u1i = min(u0i+1,WF-1);
            int v0i = min(max((int)v0,0),HF-1), v1i = min(v0i+1,HF-1);
            float w00=(1.f-du)*(1.f-dv), w01=du*(1.f-dv), w10=(1.f-du)*dv, w11=du*dv;
            int i00=v0i*WF+u0i, i01=v0i*WF+u1i, i10=v1i*WF+u0i, i11=v1i*WF+u1i;
            const _Float16* img = featsT + (size_t)cam*PP*64;
            float val = w00*(float)img[(size_t)i00*64 + lane]
                      + w01*(float)img[(size_t)i01*64 + lane]
                      + w10*(float)img[(size_t)i10*64 + lane]
                      + w11*(float)img[(size_t)i11*64 + lane];
            const float* mg = masks + cam*PP;
            float mv = w00*mg[i00] + w01*mg[i01] + w10*mg[i10] + w11*mg[i11];
            if (cam < 3) { sA += val; sA64 += mv; }
            else         { sB += val; sB64 += mv; }
        }
    }
    _Float16* Sp = S + (size_t)n*SK;
    Sp[lane]      = (_Float16)sA;     // k = 0..63
    Sp[66 + lane] = (_Float16)sB;     // k = 66..129
    if (lane == 0) { Sp[64] = (_Float16)sA64; Sp[130] = (_Float16)sB64; }
    if (lane == 1) Sp[65] = (_Float16)0.f;
    if (lane >= 3 && lane <= 30) Sp[131 + (lane-3)] = (_Float16)0.f;   // 131..158
    if (lane == 31) Sp[159] = (_Float16)(float)cnt;                    // cnt channel
}

// voxel MLP as MFMA GEMM: out[128, N] = W2[128,160] @ S[160, N]; cnt-select epilogue.
__global__ __launch_bounds__(256,2) void mlp_kernel(const _Float16* __restrict__ S,
                                                    const _Float16* __restrict__ W2,
                                                    const float* __restrict__ b_ov,
                                                    const float* __restrict__ b_no,
                                                    _Float16* __restrict__ vin) {
    constexpr int WPAD = 168;                       // padded LDS row (2-way banks)
    __shared__ __align__(16) _Float16 Wl[128*WPAD]; // 43 KB
    int tid = threadIdx.x, lane = tid & 63, wave = tid >> 6;
    int ln = lane & 15, kq = lane >> 4;
    for (int i = tid; i < 128*20; i += 256) {       // 20 granules of 8 per row
        int r = i / 20, g8 = i % 20;
        *(f16x8*)(&Wl[r*WPAD + g8*8]) = *(const f16x8*)(W2 + r*SK + g8*8);
    }
    __syncthreads();

    int nbase = blockIdx.x*128 + wave*32;           // this wave's 32 voxels
    f32x4 zero4 = {0.f,0.f,0.f,0.f};
    f32x4 acc[8][2];
    for (int m=0;m<8;m++) for (int t=0;t<2;t++) acc[m][t] = zero4;

    for (int ks = 0; ks < 5; ++ks) {
        int k0 = ks*32 + kq*8;
        f16x8 b0, b1;
        {
            int c0 = min(nbase + ln,      NVOX-1);
            int c1 = min(nbase + 16 + ln, NVOX-1);
            b0 = *(const f16x8*)(S + (size_t)c0*SK + k0);
            b1 = *(const f16x8*)(S + (size_t)c1*SK + k0);
        }
        #pragma unroll
        for (int m = 0; m < 8; ++m) {
            f16x8 a = *(const f16x8*)(&Wl[(m*16 + ln)*WPAD + k0]);
            acc[m][0] = __builtin_amdgcn_mfma_f32_16x16x32_f16(a, b0, acc[m][0], 0,0,0);
            acc[m][1] = __builtin_amdgcn_mfma_f32_16x16x32_f16(a, b1, acc[m][1], 0,0,0);
        }
    }
    #pragma unroll
    for (int t = 0; t < 2; ++t) {
        int col = nbase + t*16 + ln;
        if (col >= NVOX) continue;
        float cnt = (float)S[(size_t)col*SK + 159];
        #pragma unroll
        for (int m = 0; m < 4; ++m) {
            int oc0 = m*16 + kq*4;
            f32x4 bov = *(const f32x4*)(b_ov + oc0);
            f32x4 bno = *(const f32x4*)(b_no + oc0);
            f16x4 s;
            #pragma unroll
            for (int r = 0; r < 4; ++r) {
                float v = 0.f;
                if (cnt == 2.f)      v = eluf(acc[m][t][r]   + bov[r]);
                else if (cnt == 1.f) v = eluf(acc[m+4][t][r] + bno[r]);
                s[r] = (_Float16)v;
            }
            *(f16x4*)(vin + (size_t)col*128 + oc0) = s;
        }
    }
}

// vf_remap: x-lerp onto uniform grid; wave per voxel, lane = channel; writes ch [64,128)
__global__ __launch_bounds__(256) void remap_kernel(const float* ws, _Float16* vin) {
    int wave = threadIdx.x >> 6, lane = threadIdx.x & 63;
    int n = blockIdx.x*4 + wave;
    int x = n % XD;
    float xi = ws[OFF_XI + x];
    float fx = floorf(xi);
    float t = xi - fx;
    int x0 = min(max((int)fx,0),XD-1);
    int x1 = min(x0+1, XD-1);
    size_t rowb = (size_t)(n - x)*128;
    float r = (float)vin[rowb + (size_t)x0*128 + lane]*(1.f-t)
            + (float)vin[rowb + (size_t)x1*128 + lane]*t;
    vin[(size_t)n*128 + 64 + lane] = (_Float16)r;
}

// ---- conv3d as implicit GEMM: M=64 oc, K=128ci x 27 taps, N = one x-row ----
__global__ __launch_bounds__(256,2) void conv3d_mfma_kernel(const _Float16* __restrict__ vin,
                                                            const _Float16* __restrict__ wT,
                                                            const float* __restrict__ bias,
                                                            _Float16* __restrict__ vol) {
    __shared__ __align__(16) _Float16 Bs[9*104*36];   // [zy-row][x_ext][ic32 pad36]
    int tid = threadIdx.x, lane = tid & 63, wave = tid >> 6;
    int ln = lane & 15, kq = lane >> 4;
    int y = blockIdx.x % 100, z = blockIdx.x / 100;
    int nt0 = wave*2;
    int ntn = (wave == 3) ? 1 : 2;
    f32x4 zero4 = {0.f,0.f,0.f,0.f};
    f32x4 acc[4][2];
    for (int i=0;i<4;i++) for (int t=0;t<2;t++) acc[i][t] = zero4;

    for (int c0 = 0; c0 < 128; c0 += 32) {
        __syncthreads();
        for (int g = tid; g < 9*104*4; g += 256) {
            int ic8 = g & 3;
            int xe  = (g >> 2) % 104;
            int rid = g / (104*4);
            int xx = xe - 1, yy = y + rid%3 - 1, zz = z + rid/3 - 1;
            f16x8 val = {0,0,0,0,0,0,0,0};
            if (xx >= 0 && xx < 100 && yy >= 0 && yy < 100 && zz >= 0 && zz < 20)
                val = *(const f16x8*)(vin + (size_t)((zz*100 + yy)*100 + xx)*128 + c0 + ic8*8);
            *(f16x8*)(&Bs[(rid*104 + xe)*36 + ic8*8]) = val;
        }
        __syncthreads();
        const _Float16* wp0 = wT + c0 + kq*8;
        f16x8 a0n = *(const f16x8*)(wp0 + (ln+ 0)*128);
        f16x8 a1n = *(const f16x8*)(wp0 + (ln+16)*128);
        f16x8 a2n = *(const f16x8*)(wp0 + (ln+32)*128);
        f16x8 a3n = *(const f16x8*)(wp0 + (ln+48)*128);
        for (int tap = 0; tap < 27; ++tap) {
            f16x8 a0 = a0n, a1 = a1n, a2 = a2n, a3 = a3n;
            if (tap < 26) {
                const _Float16* wp = wT + (size_t)(tap+1)*64*128 + c0 + kq*8;
                a0n = *(const f16x8*)(wp + (ln+ 0)*128);
                a1n = *(const f16x8*)(wp + (ln+16)*128);
                a2n = *(const f16x8*)(wp + (ln+32)*128);
                a3n = *(const f16x8*)(wp + (ln+48)*128);
            }
            int dx = tap % 3, rid = tap / 3;      // rid = dz*3+dy
            for (int t = 0; t < ntn; ++t) {
                int xe = min(16*(nt0+t) + ln + dx, 103);
                f16x8 b = *(const f16x8*)(&Bs[(rid*104 + xe)*36 + kq*8]);
                acc[0][t] = __builtin_amdgcn_mfma_f32_16x16x32_f16(a0, b, acc[0][t], 0,0,0);
                acc[1][t] = __builtin_amdgcn_mfma_f32_16x16x32_f16(a1, b, acc[1][t], 0,0,0);
                acc[2][t] = __builtin_amdgcn_mfma_f32_16x16x32_f16(a2, b, acc[2][t], 0,0,0);
                acc[3][t] = __builtin_amdgcn_mfma_f32_16x16x32_f16(a3, b, acc[3][t], 0,0,0);
            }
        }
    }
    for (int i = 0; i < 4; ++i) {
        int oc0 = i*16 + kq*4;
        f32x4 bv = *(const f32x4*)(bias + oc0);
        for (int t = 0; t < ntn; ++t) {
            int x = 16*(nt0+t) + ln;
            if (x < 100) {
                size_t n = (size_t)(z*100 + y)*100 + x;
                f16x4 s;
                s[0] = (_Float16)eluf(acc[i][t][0] + bv[0]);
                s[1] = (_Float16)eluf(acc[i][t][1] + bv[1]);
                s[2] = (_Float16)eluf(acc[i][t][2] + bv[2]);
                s[3] = (_Float16)eluf(acc[i][t][3] + bv[3]);
                *(f16x4*)(vol + n*64 + oc0) = s;
            }
        }
    }
}

// ---- project: two-phase (unchanged) ----
__global__ __launch_bounds__(256) void project_kernel(const float* ws, const float* ext,
                                                      const _Float16* vol, _Float16* proj) {
    __shared__ unsigned s_off[256][8];
    __shared__ float    s_w[256][8];
    int tid = threadIdx.x;
    int item = blockIdx.x*256 + tid;       // item = (cam*3520 + p)*50 + d
    int d = item % 50;
    int p = (item/50) % 3520;
    int cam = item / (50*3520);
    {
        float uu = (float)(p % WF), vv = (float)(p / WF);
        const float* KI = ws + OFF_K3I + cam*9;
        float dxr = KI[0]*uu + KI[1]*vv + KI[2];
        float dyr = KI[3]*uu + KI[4]*vv + KI[5];
        float dzr = KI[6]*uu + KI[7]*vv + KI[8];
        float dep = ws[OFF_DBIN + d];
        float cx = dxr*dep, cy = dyr*dep, cz = dzr*dep;
        const float* E = ext + cam*16;
        float wx = E[0]*cx + E[1]*cy + E[2]*cz  + E[3];
        float wy = E[4]*cx + E[5]*cy + E[6]*cz  + E[7];
        float wz = E[8]*cx + E[9]*cy + E[10]*cz + E[11];
        float ex0 = 1.0f/(AX_A + 99.0f*AX_STEP);
        float exN = 1.0f/AX_A;
        float qc = fminf(fmaxf(wx, ex0), exN - 1e-6f);
        float f = 99.0f - (1.0f/qc - AX_A)/AX_STEP;
        int k = min(max((int)floorf(f),0),98);
        float exk  = 1.0f/(AX_A + (float)(99-k)*AX_STEP);
        float exk1 = 1.0f/(AX_A + (float)(98-k)*AX_STEP);
        float xi = (float)k + (qc - exk)/(exk1 - exk + 1e-12f);
        float yi = (wy + 25.0f) * (99.0f/49.5f);
        float zi = (wz + 3.0f)  * (19.0f/5.7f);
        float scale = ((wx >= 2.0f) && (wx <= 51.5f) && (yi >= 0.f) && (yi <= 99.f)
                       && (zi >= 0.f) && (zi <= 19.f)) ? 1.f : 0.f;
        float fx = floorf(xi), fy = floorf(yi), fz = floorf(zi);
        float tx = xi-fx, ty = yi-fy, tz = zi-fz;
        int x0 = min(max((int)fx,0),XD-1), x1 = min(x0+1,XD-1);
        int y0 = min(max((int)fy,0),YD-1), y1 = min(y0+1,YD-1);
        int z0 = min(max((int)fz,0),ZD-1), z1 = min(z0+1,ZD-1);
        s_off[tid][0] = (unsigned)(((z0*YD+y0)*XD+x0)*64); s_w[tid][0] = (1.f-tx)*(1.f-ty)*(1.f-tz)*scale;
        s_off[tid][1] = (unsigned)(((z0*YD+y0)*XD+x1)*64); s_w[tid][1] = tx*(1.f-ty)*(1.f-tz)*scale;
        s_off[tid][2] = (unsigned)(((z0*YD+y1)*XD+x0)*64); s_w[tid][2] = (1.f-tx)*ty*(1.f-tz)*scale;
        s_off[tid][3] = (unsigned)(((z0*YD+y1)*XD+x1)*64); s_w[tid][3] = tx*ty*(1.f-tz)*scale;
        s_off[tid][4] = (unsigned)(((z1*YD+y0)*XD+x0)*64); s_w[tid][4] = (1.f-tx)*(1.f-ty)*tz*scale;
        s_off[tid][5] = (unsigned)(((z1*YD+y0)*XD+x1)*64); s_w[tid][5] = tx*(1.f-ty)*tz*scale;
        s_off[tid][6] = (unsigned)(((z1*YD+y1)*XD+x0)*64); s_w[tid][6] = (1.f-tx)*ty*tz*scale;
        s_off[tid][7] = (unsigned)(((z1*YD+y1)*XD+x1)*64); s_w[tid][7] = tx*ty*tz*scale;
    }
    __syncthreads();
    int wave = tid >> 6, lane = tid & 63;
    size_t outbase = (size_t)blockIdx.x*256 + wave*64;
    for (int j = 0; j < 64; ++j) {
        int it = wave*64 + j;
        float a = 0.f;
        #pragma unroll
        for (int c = 0; c < 8; ++c)
            a += s_w[it][c] * (float)vol[s_off[it][c] + lane];
        proj[(outbase + j)*64 + lane] = (_Float16)a;
    }
}

// ---- conv2d implicit GEMM: EXACT R5 configuration (best measured: ~731 us).
//      Do not modify: R6/R7/R8/R10 variants all regressed (journal).
template<int ICN, bool OUT16>
__global__ __launch_bounds__(256,2) void conv2d_mfma_kernel(const _Float16* __restrict__ in,
                                                            const _Float16* __restrict__ wT,
                                                            const float* __restrict__ bias,
                                                            void* __restrict__ outp) {
    constexpr int NCH = ICN/32;
    constexpr int NSLOT = 6;                          // ceil(4*82*4 / 256)
    __shared__ __align__(16) _Float16 Bs[2][4*82*36]; // 2 x 23.6 KB
    int tid = threadIdx.x, lane = tid & 63, wave = tid >> 6;
    int wm = wave >> 1, wn = wave & 1;
    int ln = lane & 15, kq = lane >> 4;
    int bid = blockIdx.x;
    int ocq = bid & 3;
    int rest = bid >> 2;
    int cam = rest % 6;
    int h0 = (rest / 6)*2;
    int ocb = ocq*64 + wm*32;
    size_t campix0 = (size_t)cam*3520;
    f32x4 zero4 = {0.f,0.f,0.f,0.f};
    f32x4 acc[2][5];
    for (int i=0;i<2;i++) for (int t=0;t<5;t++) acc[i][t] = zero4;

    // staging slot descriptors
    size_t soff[NSLOT];
    int    slds[NSLOT];
    bool   sok[NSLOT];
    #pragma unroll
    for (int i = 0; i < NSLOT; ++i) {
        int g = tid + i*256;
        if (g < 4*82*4) {
            int ic8 = g & 3;
            int we  = (g >> 2) % 82;
            int re  = g / (82*4);
            int h = h0 - 1 + re;
            int w = we - 1;
            sok[i]  = (h >= 0 && h < HF && w >= 0 && w < WF);
            soff[i] = (campix0 + h*80 + w)*(size_t)ICN + ic8*8;
            slds[i] = (re*82 + we)*36 + ic8*8;
        } else { sok[i] = false; soff[i] = 0; slds[i] = -1; }
    }

    // prefetch chunk 0 into registers
    f16x8 sreg[NSLOT];
    #pragma unroll
    for (int i = 0; i < NSLOT; ++i) {
        f16x8 v = {0,0,0,0,0,0,0,0};
        if (sok[i]) v = *(const f16x8*)(in + soff[i]);
        sreg[i] = v;
    }

    const _Float16* wbase0 = wT + (size_t)ocb*ICN + kq*8;
    for (int c = 0; c < NCH; ++c) {
        int buf = c & 1;
        #pragma unroll
        for (int i = 0; i < NSLOT; ++i)
            if (slds[i] >= 0) *(f16x8*)(&Bs[buf][slds[i]]) = sreg[i];
        __syncthreads();
        if (c + 1 < NCH) {
            int c1 = (c+1)*32;
            #pragma unroll
            for (int i = 0; i < NSLOT; ++i) {
                f16x8 v = {0,0,0,0,0,0,0,0};
                if (sok[i]) v = *(const f16x8*)(in + soff[i] + c1);
                sreg[i] = v;
            }
        }
        // batched A preload for this chunk: 18 fragments, one wait
        f16x8 A0[9], A1[9];
        const _Float16* wb = wbase0 + c*32;
        #pragma unroll
        for (int tap = 0; tap < 9; ++tap) {
            const _Float16* wp = wb + (size_t)tap*256*ICN;
            A0[tap] = *(const f16x8*)(wp + (size_t)(ln+ 0)*ICN);
            A1[tap] = *(const f16x8*)(wp + (size_t)(ln+16)*ICN);
        }
        #pragma unroll
        for (int tap = 0; tap < 9; ++tap) {
            int ky = tap/3, kx = tap%3;
            int rbase = (wn + ky)*82 + ln + kx;
            #pragma unroll
            for (int t = 0; t < 5; ++t) {
                f16x8 b = *(const f16x8*)(&Bs[buf][(rbase + 16*t)*36 + kq*8]);
                acc[0][t] = __builtin_amdgcn_mfma_f32_16x16x32_f16(A0[tap], b, acc[0][t], 0,0,0);
                acc[1][t] = __builtin_amdgcn_mfma_f32_16x16x32_f16(A1[tap], b, acc[1][t], 0,0,0);
            }
        }
    }
    int pixrow = h0 + wn;
    for (int i = 0; i < 2; ++i) {
        int oc0 = ocb + i*16 + kq*4;
        f32x4 bv = *(const f32x4*)(bias + oc0);
        for (int t = 0; t < 5; ++t) {
            int pix = pixrow*80 + 16*t + ln;
            float v0 = eluf(acc[i][t][0] + bv[0]);
            float v1 = eluf(acc[i][t][1] + bv[1]);
            float v2 = eluf(acc[i][t][2] + bv[2]);
            float v3 = eluf(acc[i][t][3] + bv[3]);
            if (OUT16) {
                f16x4 s; s[0]=(_Float16)v0; s[1]=(_Float16)v1; s[2]=(_Float16)v2; s[3]=(_Float16)v3;
                *(f16x4*)((_Float16*)outp + (campix0 + pix)*256 + oc0) = s;
            } else {
                float* op = (float*)outp + ((size_t)(cam*256 + oc0))*PP + pix;
                op[0] = v0; op[PP] = v1; op[2*PP] = v2; op[3*PP] = v3;
            }
        }
    }
}

extern "C" void kernel_launch(void* const* d_in, const int* in_sizes, int n_in,
                              void* d_out, int out_size, void* d_ws, size_t ws_size,
                              hipStream_t stream) {
    const float* feats = (const float*)d_in[0];
    const float* masks = (const float*)d_in[1];
    const float* K     = (const float*)d_in[2];
    const float* ext   = (const float*)d_in[3];
    const float* w_ov  = (const float*)d_in[4];
    const float* b_ov  = (const float*)d_in[5];
    const float* w_no  = (const float*)d_in[6];
    const float* b_no  = (const float*)d_in[7];
    const float* w_fu  = (const float*)d_in[8];
    const float* b_fu  = (const float*)d_in[9];
    const float* w_r1  = (const float*)d_in[10];
    const float* b_r1  = (const float*)d_in[11];
    const float* w_r2  = (const float*)d_in[12];
    const float* b_r2  = (const float*)d_in[13];
    char* base = (char*)d_ws;
    float*    wsf  = (float*)base;
    _Float16* vol  = (_Float16*)(base + B_VOL);
    _Float16* wT1  = (_Float16*)(base + B_WT1);
    _Float16* h    = (_Float16*)(base + B_H);
    _Float16* vin  = (_Float16*)(base + B_VIN);
    _Float16* proj = (_Float16*)(base + B_PROJ);
    _Float16* wT2  = (_Float16*)(base + B_WT2);
    _Float16* wT3  = (_Float16*)(base + B_WT3);
    _Float16* Sbuf = (_Float16*)(base + B_S);
    _Float16* W2   = (_Float16*)(base + B_W2);
    _Float16* fT   = (_Float16*)(base + B_FT);
    float* out = (float*)d_out;

    setup_kernel<<<1, 256, 0, stream>>>(K, ext, wsf);
    tw3_kernel<<<(27*64*128)/256, 256, 0, stream>>>(w_fu, wT3);
    tw4_kernel<<<(128*SK)/256, 256, 0, stream>>>(w_ov, w_no, W2);
    tw5_kernel<<<(NCAM*PP*64)/256, 256, 0, stream>>>(feats, fT);
    gather_kernel<<<NVOX/4, 256, 0, stream>>>(fT, masks, wsf, Sbuf);
    mlp_kernel<<<(NVOX + 127)/128, 256, 0, stream>>>(Sbuf, W2, b_ov, b_no, vin);
    remap_kernel<<<NVOX/4, 256, 0, stream>>>(wsf, vin);
    conv3d_mfma_kernel<<<ZD*YD, 256, 0, stream>>>(vin, wT3, b_fu, vol);
    project_kernel<<<(NCAM*PP*DBN)/256, 256, 0, stream>>>(wsf, ext, vol, proj);
    tw1_kernel<<<(9*256*3200)/256, 256, 0, stream>>>(w_r1, wT1);
    conv2d_mfma_kernel<3200, true><<<4*NCAM*22, 256, 0, stream>>>(proj, wT1, b_r1, h);
    tw2_kernel<<<(9*256*256)/256, 256, 0, stream>>>(w_r2, wT2);
    conv2d_mfma_kernel<256, false><<<4*NCAM*22, 256, 0, stream>>>(h, wT2, b_r2, out);
}